// Round 1
// baseline (567.157 us; speedup 1.0000x reference)
//
#include <hip/hip_runtime.h>
#include <hip/hip_bf16.h>
#include <cstdio>
#include <cstdint>

#define TNUM 2048
#define DDIM 768
#define HDIM 3072
#define ENUM 8

typedef __attribute__((ext_vector_type(8))) __bf16 bf16x8;
typedef __attribute__((ext_vector_type(4))) float f32x4;

__device__ __forceinline__ unsigned short f2bf(float f) {
    __bf16 h = (__bf16)f;            // RNE
    unsigned short u;
    __builtin_memcpy(&u, &h, 2);
    return u;
}

// async global->LDS, 16B per lane; LDS dest = wave-uniform base + lane*16
__device__ __forceinline__ void async_cp16(const unsigned short* g, unsigned short* l) {
    __builtin_amdgcn_global_load_lds((const __attribute__((address_space(1))) void*)g,
                                     (__attribute__((address_space(3))) void*)l,
                                     16, 0, 0);
}

// ---------------- cast x -> bf16 ----------------
__global__ void cast_x_kernel(const float* __restrict__ x, unsigned short* __restrict__ xb) {
    int i = (blockIdx.x * 256 + threadIdx.x) * 8;
    float4 a = *(const float4*)(x + i);
    float4 b = *(const float4*)(x + i + 4);
    ushort4 lo = make_ushort4(f2bf(a.x), f2bf(a.y), f2bf(a.z), f2bf(a.w));
    ushort4 hi = make_ushort4(f2bf(b.x), f2bf(b.y), f2bf(b.z), f2bf(b.w));
    *(ushort4*)(xb + i) = lo;
    *(ushort4*)(xb + i + 4) = hi;
}

// ---------------- transpose + cast weights to bf16 [n][k] ----------------
// z<8: W1[e] (768x3072) -> W1t[e] (3072x768);  8<=z<16: W2[e] (3072x768) -> W2t[e] (768x3072)
// z=16: Ws1 -> Ws1t; z=17: Ws2 -> Ws2t
__global__ void transw_kernel(const float* __restrict__ W1, const float* __restrict__ W2,
                              const float* __restrict__ Ws1, const float* __restrict__ Ws2,
                              unsigned short* __restrict__ W1t, unsigned short* __restrict__ W2t,
                              unsigned short* __restrict__ Ws1t, unsigned short* __restrict__ Ws2t) {
    int z = blockIdx.z;
    const float* in; unsigned short* out; int R, C;
    if (z < 8)       { in = W1 + (size_t)z * DDIM * HDIM; out = W1t + (size_t)z * HDIM * DDIM; R = DDIM; C = HDIM; }
    else if (z < 16) { int e = z - 8; in = W2 + (size_t)e * HDIM * DDIM; out = W2t + (size_t)e * DDIM * HDIM; R = HDIM; C = DDIM; }
    else if (z == 16){ in = Ws1; out = Ws1t; R = DDIM; C = HDIM; }
    else             { in = Ws2; out = Ws2t; R = HDIM; C = DDIM; }
    int c0 = blockIdx.x * 32, r0 = blockIdx.y * 32;
    if (c0 >= C || r0 >= R) return;
    __shared__ unsigned short tile[32][34];
    int tx = threadIdx.x, ty = threadIdx.y;
    #pragma unroll
    for (int k = 0; k < 4; k++) {
        int r = r0 + ty + k * 8;
        tile[ty + k * 8][tx] = f2bf(in[(size_t)r * C + c0 + tx]);
    }
    __syncthreads();
    #pragma unroll
    for (int k = 0; k < 4; k++) {
        int c = c0 + ty + k * 8;
        out[(size_t)c * R + r0 + tx] = tile[tx][ty + k * 8];
    }
}

// ---------------- router: one wave per token ----------------
__global__ void router_kernel(const float* __restrict__ x, const float* __restrict__ noise,
                              const float* __restrict__ Wr, const float* __restrict__ br,
                              int* __restrict__ counts, int* __restrict__ list, float* __restrict__ gate) {
    int lane = threadIdx.x & 63;
    int t = blockIdx.x * 4 + (threadIdx.x >> 6);
    float acc[8];
    #pragma unroll
    for (int e = 0; e < 8; e++) acc[e] = 0.f;
    #pragma unroll
    for (int i = 0; i < 12; i++) {
        int d = i * 64 + lane;
        float xv = x[t * DDIM + d];
        float4 w0 = *(const float4*)(Wr + d * 8);
        float4 w1 = *(const float4*)(Wr + d * 8 + 4);
        acc[0] += xv * w0.x; acc[1] += xv * w0.y; acc[2] += xv * w0.z; acc[3] += xv * w0.w;
        acc[4] += xv * w1.x; acc[5] += xv * w1.y; acc[6] += xv * w1.z; acc[7] += xv * w1.w;
    }
    #pragma unroll
    for (int e = 0; e < 8; e++) {
        #pragma unroll
        for (int off2 = 32; off2 >= 1; off2 >>= 1)
            acc[e] += __shfl_xor(acc[e], off2, 64);
    }
    if (lane == 0) {
        float lg[8];
        #pragma unroll
        for (int e = 0; e < 8; e++) lg[e] = acc[e] + br[e] + 0.1f * noise[t * 8 + e];
        int e0 = 0;
        #pragma unroll
        for (int e = 1; e < 8; e++) if (lg[e] > lg[e0]) e0 = e;
        int e1 = -1;
        #pragma unroll
        for (int e = 0; e < 8; e++) if (e != e0 && (e1 < 0 || lg[e] > lg[e1])) e1 = e;
        float m = fmaxf(lg[e0], lg[e1]);
        float p0 = expf(lg[e0] - m), p1 = expf(lg[e1] - m);
        float inv = 1.f / (p0 + p1);
        int s0 = atomicAdd(&counts[e0], 1);
        list[e0 * TNUM + s0] = t;
        gate[e0 * TNUM + s0] = p0 * inv;
        int s1 = atomicAdd(&counts[e1], 1);
        list[e1 * TNUM + s1] = t;
        gate[e1 * TNUM + s1] = p1 * inv;
    }
}

// ---------------- prefix offsets + mixing scalars ----------------
__global__ void finalize_kernel(const int* __restrict__ counts, int* __restrict__ offs,
                                const float* __restrict__ alpha, const float* __restrict__ beta,
                                float* __restrict__ scal) {
    int s = 0;
    for (int e = 0; e < 8; e++) { offs[e] = s; s += counts[e]; }
    offs[8] = s;   // == 4096
    float a = alpha[0], b = beta[0];
    float m = fmaxf(a, b);
    float ea = expf(a - m), eb = expf(b - m);
    float inv = 1.f / (ea + eb);
    scal[0] = ea * inv;   // pairs with shared expert
    scal[1] = eb * inv;   // pairs with moe out
}

// ---------------- GEMM layer 1: h = leaky(x @ W1[e] + b1[e]) ----------------
// grid (16 Mtiles, 24 Ntiles, 9); z==8 => shared expert over all tokens
__global__ __launch_bounds__(256, 2)
void ffn1_kernel(const unsigned short* __restrict__ xb,
                 const unsigned short* __restrict__ W1t,   // [8][3072][768]
                 const unsigned short* __restrict__ Ws1t,  // [3072][768]
                 const float* __restrict__ b1, const float* __restrict__ bs1,
                 const int* __restrict__ counts, const int* __restrict__ offs,
                 const int* __restrict__ list,
                 unsigned short* __restrict__ hbuf) {      // [6144][3072]
    int z = blockIdx.z;
    int cnt = (z < 8) ? counts[z] : TNUM;
    int m0 = blockIdx.x * 128;
    if (m0 >= cnt) return;
    int n0 = blockIdx.y * 128;
    int hbase = (z < 8) ? offs[z] : 2 * TNUM;
    const unsigned short* Bmat = (z < 8) ? (W1t + (size_t)z * HDIM * DDIM) : Ws1t;
    const float* bias = (z < 8) ? (b1 + z * HDIM) : bs1;

    __shared__ __align__(16) unsigned short As[128 * 32];
    __shared__ __align__(16) unsigned short Bs[128 * 32];

    int tid = threadIdx.x;
    int wid = tid >> 6, lane = tid & 63;
    int l15 = lane & 15, quad = lane >> 4;
    int wm = (wid & 1) * 64, wn = (wid >> 1) * 64;

    int c0 = wid * 2, c1 = c0 + 1;
    int lsub = lane >> 2;          // 0..15 : sub-row in 16-row chunk
    int kpart = (lane & 3) * 8;    // 0,8,16,24 : bf16 offset in 32-wide k

    int r0 = m0 + c0 * 16 + lsub;
    int r1 = m0 + c1 * 16 + lsub;
    int rc0 = min(r0, cnt - 1);
    int rc1 = min(r1, cnt - 1);
    int t0 = (z < 8) ? list[z * TNUM + rc0] : rc0;
    int t1 = (z < 8) ? list[z * TNUM + rc1] : rc1;
    const unsigned short* gA0 = xb + (size_t)t0 * DDIM + kpart;
    const unsigned short* gA1 = xb + (size_t)t1 * DDIM + kpart;
    const unsigned short* gB0 = Bmat + (size_t)(n0 + c0 * 16 + lsub) * DDIM + kpart;
    const unsigned short* gB1 = Bmat + (size_t)(n0 + c1 * 16 + lsub) * DDIM + kpart;
    unsigned short* lA0 = As + c0 * 512;
    unsigned short* lA1 = As + c1 * 512;
    unsigned short* lB0 = Bs + c0 * 512;
    unsigned short* lB1 = Bs + c1 * 512;

    f32x4 zero = {0.f, 0.f, 0.f, 0.f};
    f32x4 acc[4][4];
    #pragma unroll
    for (int i = 0; i < 4; i++)
        #pragma unroll
        for (int j = 0; j < 4; j++) acc[i][j] = zero;

    #pragma unroll 1
    for (int kt = 0; kt < DDIM / 32; kt++) {
        int k0 = kt * 32;
        __syncthreads();
        async_cp16(gA0 + k0, lA0);
        async_cp16(gA1 + k0, lA1);
        async_cp16(gB0 + k0, lB0);
        async_cp16(gB1 + k0, lB1);
        __syncthreads();
        bf16x8 af[4], bv[4];
        #pragma unroll
        for (int i = 0; i < 4; i++)
            af[i] = *(const bf16x8*)(As + (wm + i * 16 + l15) * 32 + quad * 8);
        #pragma unroll
        for (int j = 0; j < 4; j++)
            bv[j] = *(const bf16x8*)(Bs + (wn + j * 16 + l15) * 32 + quad * 8);
        #pragma unroll
        for (int i = 0; i < 4; i++)
            #pragma unroll
            for (int j = 0; j < 4; j++)
                acc[i][j] = __builtin_amdgcn_mfma_f32_16x16x32_bf16(af[i], bv[j], acc[i][j], 0, 0, 0);
    }

    #pragma unroll
    for (int i = 0; i < 4; i++) {
        int rbase = m0 + wm + i * 16 + quad * 4;
        #pragma unroll
        for (int j = 0; j < 4; j++) {
            int gc = n0 + wn + j * 16 + l15;
            float bvl = bias[gc];
            #pragma unroll
            for (int r = 0; r < 4; r++) {
                int gr = rbase + r;
                if (gr < cnt) {
                    float v = acc[i][j][r] + bvl;
                    v = v > 0.f ? v : 0.01f * v;
                    hbuf[(size_t)(hbase + gr) * HDIM + gc] = f2bf(v);
                }
            }
        }
    }
}

// ---------------- GEMM layer 2: out += scale * (h @ W2[e] + b2[e]) ----------------
// grid (16 Mtiles, 6 Ntiles, 18); z = zz%9 expert (8=shared), kh = zz/9 split-K half
__global__ __launch_bounds__(256, 2)
void ffn2_kernel(const unsigned short* __restrict__ hbuf,
                 const unsigned short* __restrict__ W2t,   // [8][768][3072]
                 const unsigned short* __restrict__ Ws2t,  // [768][3072]
                 const float* __restrict__ b2, const float* __restrict__ bs2,
                 const int* __restrict__ counts, const int* __restrict__ offs,
                 const int* __restrict__ list, const float* __restrict__ gate,
                 const float* __restrict__ scal,
                 float* __restrict__ out) {
    int zz = blockIdx.z;
    int z = zz % 9, kh = zz / 9;
    int cnt = (z < 8) ? counts[z] : TNUM;
    int m0 = blockIdx.x * 128;
    if (m0 >= cnt) return;
    int n0 = blockIdx.y * 128;
    int hbase = (z < 8) ? offs[z] : 2 * TNUM;
    const unsigned short* Bmat = (z < 8) ? (W2t + (size_t)z * DDIM * HDIM) : Ws2t;
    const float* bias = (z < 8) ? (b2 + z * DDIM) : bs2;

    __shared__ __align__(16) unsigned short As[128 * 32];
    __shared__ __align__(16) unsigned short Bs[128 * 32];

    int tid = threadIdx.x;
    int wid = tid >> 6, lane = tid & 63;
    int l15 = lane & 15, quad = lane >> 4;
    int wm = (wid & 1) * 64, wn = (wid >> 1) * 64;

    int c0 = wid * 2, c1 = c0 + 1;
    int lsub = lane >> 2;
    int kpart = (lane & 3) * 8;

    int r0 = m0 + c0 * 16 + lsub;
    int r1 = m0 + c1 * 16 + lsub;
    int rc0 = min(r0, cnt - 1);
    int rc1 = min(r1, cnt - 1);
    int kbase = kh * (HDIM / 2);
    const unsigned short* gA0 = hbuf + (size_t)(hbase + rc0) * HDIM + kbase + kpart;
    const unsigned short* gA1 = hbuf + (size_t)(hbase + rc1) * HDIM + kbase + kpart;
    const unsigned short* gB0 = Bmat + (size_t)(n0 + c0 * 16 + lsub) * HDIM + kbase + kpart;
    const unsigned short* gB1 = Bmat + (size_t)(n0 + c1 * 16 + lsub) * HDIM + kbase + kpart;
    unsigned short* lA0 = As + c0 * 512;
    unsigned short* lA1 = As + c1 * 512;
    unsigned short* lB0 = Bs + c0 * 512;
    unsigned short* lB1 = Bs + c1 * 512;

    f32x4 zero = {0.f, 0.f, 0.f, 0.f};
    f32x4 acc[4][4];
    #pragma unroll
    for (int i = 0; i < 4; i++)
        #pragma unroll
        for (int j = 0; j < 4; j++) acc[i][j] = zero;

    #pragma unroll 1
    for (int kt = 0; kt < (HDIM / 2) / 32; kt++) {
        int k0 = kt * 32;
        __syncthreads();
        async_cp16(gA0 + k0, lA0);
        async_cp16(gA1 + k0, lA1);
        async_cp16(gB0 + k0, lB0);
        async_cp16(gB1 + k0, lB1);
        __syncthreads();
        bf16x8 af[4], bv[4];
        #pragma unroll
        for (int i = 0; i < 4; i++)
            af[i] = *(const bf16x8*)(As + (wm + i * 16 + l15) * 32 + quad * 8);
        #pragma unroll
        for (int j = 0; j < 4; j++)
            bv[j] = *(const bf16x8*)(Bs + (wn + j * 16 + l15) * 32 + quad * 8);
        #pragma unroll
        for (int i = 0; i < 4; i++)
            #pragma unroll
            for (int j = 0; j < 4; j++)
                acc[i][j] = __builtin_amdgcn_mfma_f32_16x16x32_bf16(af[i], bv[j], acc[i][j], 0, 0, 0);
    }

    float ws_sc = scal[0], wm_sc = scal[1];
    #pragma unroll
    for (int i = 0; i < 4; i++) {
        int rbase = m0 + wm + i * 16 + quad * 4;
        #pragma unroll
        for (int r = 0; r < 4; r++) {
            int gr = rbase + r;
            if (gr >= cnt) continue;
            int t; float scale;
            if (z < 8) { t = list[z * TNUM + gr]; scale = wm_sc * gate[z * TNUM + gr]; }
            else       { t = gr; scale = ws_sc; }
            float* orow = out + (size_t)t * DDIM;
            #pragma unroll
            for (int j = 0; j < 4; j++) {
                int gc = n0 + wn + j * 16 + l15;
                float bvl = (kh == 0) ? bias[gc] : 0.f;
                atomicAdd(orow + gc, (acc[i][j][r] + bvl) * scale);
            }
        }
    }
}

extern "C" void kernel_launch(void* const* d_in, const int* in_sizes, int n_in,
                              void* d_out, int out_size, void* d_ws, size_t ws_size,
                              hipStream_t stream) {
    const float* x     = (const float*)d_in[0];
    const float* noise = (const float*)d_in[1];
    const float* Wr    = (const float*)d_in[2];
    const float* br    = (const float*)d_in[3];
    const float* W1    = (const float*)d_in[4];
    const float* b1    = (const float*)d_in[5];
    const float* W2    = (const float*)d_in[6];
    const float* b2    = (const float*)d_in[7];
    const float* Ws1   = (const float*)d_in[8];
    const float* bs1   = (const float*)d_in[9];
    const float* Ws2   = (const float*)d_in[10];
    const float* bs2   = (const float*)d_in[11];
    const float* alpha = (const float*)d_in[12];
    const float* beta  = (const float*)d_in[13];

    char* ws = (char*)d_ws;
    size_t off = 0;
    auto alloc = [&](size_t bytes) -> char* {
        char* p = ws + off;
        off = (off + bytes + 255) & ~(size_t)255;
        return p;
    };
    int*   counts = (int*)  alloc(ENUM * 4);
    int*   offs   = (int*)  alloc(16 * 4);
    float* scal   = (float*)alloc(2 * 4);
    int*   list   = (int*)  alloc((size_t)ENUM * TNUM * 4);
    float* gate   = (float*)alloc((size_t)ENUM * TNUM * 4);
    unsigned short* xb   = (unsigned short*)alloc((size_t)TNUM * DDIM * 2);
    unsigned short* W1t  = (unsigned short*)alloc((size_t)ENUM * HDIM * DDIM * 2);
    unsigned short* W2t  = (unsigned short*)alloc((size_t)ENUM * DDIM * HDIM * 2);
    unsigned short* Ws1t = (unsigned short*)alloc((size_t)HDIM * DDIM * 2);
    unsigned short* Ws2t = (unsigned short*)alloc((size_t)DDIM * HDIM * 2);
    unsigned short* hbuf = (unsigned short*)alloc((size_t)(3 * TNUM) * HDIM * 2);
    if (off > ws_size) {
        fprintf(stderr, "kernel_launch: workspace too small (need %zu, have %zu)\n", off, ws_size);
        return;
    }

    hipMemsetAsync(d_out, 0, (size_t)out_size * sizeof(float), stream);
    hipMemsetAsync(counts, 0, ENUM * 4, stream);

    cast_x_kernel<<<dim3((TNUM * DDIM / 8) / 256), dim3(256), 0, stream>>>(x, xb);
    transw_kernel<<<dim3(96, 96, 18), dim3(32, 8), 0, stream>>>(W1, W2, Ws1, Ws2, W1t, W2t, Ws1t, Ws2t);
    router_kernel<<<dim3(TNUM / 4), dim3(256), 0, stream>>>(x, noise, Wr, br, counts, list, gate);
    finalize_kernel<<<dim3(1), dim3(1), 0, stream>>>(counts, offs, alpha, beta, scal);
    ffn1_kernel<<<dim3(16, 24, 9), dim3(256), 0, stream>>>(xb, W1t, Ws1t, b1, bs1, counts, offs, list, hbuf);
    ffn2_kernel<<<dim3(16, 6, 18), dim3(256), 0, stream>>>(hbuf, W2t, Ws2t, b2, bs2, counts, offs, list, gate, scal, (float*)d_out);
}